// Round 1
// baseline (2146.462 us; speedup 1.0000x reference)
//
#include <hip/hip_runtime.h>
#include <math.h>

#define B_   16
#define I_   2048
#define AIN_ 16
#define O_   64
#define J_   2048     // O*A_OUT
#define IPB_ 8        // i's per block
#define NBLK_ 256     // I_/IPB_

// -------------------------------------------------------------------------
// pass_kernel<PASS>: one full streaming pass over W, recomputing votes.
//   PASS 0: route = 1/64 (softmax of zero logits)  -> partial preact
//   PASS 1: dist = votes.act0; logits := dist; route = softmax(dist)
//   PASS 2: dist = votes.act1; route = softmax(logits + dist)
// Thread tid owns columns j0=tid, j1=tid+1024 for ALL 16 batches (registers).
// Block owns i in [blk*8, blk*8+8). Partial preact -> part[blk][b][j].
// -------------------------------------------------------------------------
template<int PASS>
__global__ __launch_bounds__(1024) void pass_kernel(
    const float* __restrict__ x, const float* __restrict__ W,
    const float* __restrict__ act_in, float* __restrict__ part,
    float* __restrict__ logits)
{
  __shared__ float x_lds[IPB_ * B_ * AIN_];   // 8 KB, [il][b][a]
  __shared__ float d_lds[B_ * O_];            // 4 KB, distances [b][o]
  __shared__ float r_lds[B_ * O_];            // 4 KB, route     [b][o]

  const int tid = threadIdx.x;
  const int blk = blockIdx.x;
  const int i0  = blk * IPB_;

  // stage x chunk for all 8 i's (coalesced)
  for (int e = tid; e < IPB_ * B_ * AIN_; e += 1024) {
    int b = e >> 7, il = (e >> 4) & 7, a = e & 15;
    x_lds[il * 256 + b * 16 + a] =
        x[(size_t)b * (I_ * AIN_) + (size_t)(i0 + il) * AIN_ + a];
  }
  __syncthreads();

  const int j0 = tid, j1 = tid + 1024;
  const int og = tid >> 5;      // o-group of j0 (0..31); j1 -> og+32
  const int lg = tid & 31;      // lane within o-group
  const int b2 = tid >> 6;      // softmax-stage mapping: wave = one b
  const int o2 = tid & 63;

  float acc0[16], acc1[16];
  #pragma unroll
  for (int b = 0; b < 16; ++b) { acc0[b] = 0.f; acc1[b] = 0.f; }

  for (int il = 0; il < IPB_; ++il) {
    const int i = i0 + il;
    const float* __restrict__ Wi = W + (size_t)i * (AIN_ * J_);
    const float4* __restrict__ xq = (const float4*)(x_lds) + il * 64;

    // ---- votes: v[b] = sum_a' x[b,a'] * W[i,a',j]  (W element -> 1 reg) ----
    float v0[16], v1[16];
    #pragma unroll
    for (int b = 0; b < 16; ++b) { v0[b] = 0.f; v1[b] = 0.f; }

    #pragma unroll
    for (int a4 = 0; a4 < 4; ++a4) {
      float w00 = Wi[(size_t)(a4 * 4 + 0) * J_ + j0];
      float w01 = Wi[(size_t)(a4 * 4 + 1) * J_ + j0];
      float w02 = Wi[(size_t)(a4 * 4 + 2) * J_ + j0];
      float w03 = Wi[(size_t)(a4 * 4 + 3) * J_ + j0];
      float w10 = Wi[(size_t)(a4 * 4 + 0) * J_ + j1];
      float w11 = Wi[(size_t)(a4 * 4 + 1) * J_ + j1];
      float w12 = Wi[(size_t)(a4 * 4 + 2) * J_ + j1];
      float w13 = Wi[(size_t)(a4 * 4 + 3) * J_ + j1];
      #pragma unroll
      for (int b = 0; b < 16; ++b) {
        float4 xv = xq[b * 4 + a4];     // LDS broadcast (same addr, 16 lanes)
        v0[b] = fmaf(xv.x, w00, v0[b]);
        v0[b] = fmaf(xv.y, w01, v0[b]);
        v0[b] = fmaf(xv.z, w02, v0[b]);
        v0[b] = fmaf(xv.w, w03, v0[b]);
        v1[b] = fmaf(xv.x, w10, v1[b]);
        v1[b] = fmaf(xv.y, w11, v1[b]);
        v1[b] = fmaf(xv.z, w12, v1[b]);
        v1[b] = fmaf(xv.w, w13, v1[b]);
      }
    }

    if (PASS == 0) {
      #pragma unroll
      for (int b = 0; b < 16; ++b) { acc0[b] += v0[b]; acc1[b] += v1[b]; }
    } else {
      // ---- distances[b][o] = sum_a v*act : 32-lane xor-butterfly per b ----
      #pragma unroll
      for (int b = 0; b < 16; ++b) {
        float c0 = v0[b] * act_in[b * J_ + j0];
        c0 += __shfl_xor(c0, 1);  c0 += __shfl_xor(c0, 2);
        c0 += __shfl_xor(c0, 4);  c0 += __shfl_xor(c0, 8);
        c0 += __shfl_xor(c0, 16);
        float c1 = v1[b] * act_in[b * J_ + j1];
        c1 += __shfl_xor(c1, 1);  c1 += __shfl_xor(c1, 2);
        c1 += __shfl_xor(c1, 4);  c1 += __shfl_xor(c1, 8);
        c1 += __shfl_xor(c1, 16);
        if (lg == b) {
          d_lds[b * 64 + og]      = c0;
          d_lds[b * 64 + og + 32] = c1;
        }
      }
      __syncthreads();

      // ---- softmax over o (one wave = one b; lane = o) ----
      float ell = d_lds[tid];                              // d[b2][o2]
      if (PASS == 2) ell += logits[((size_t)b2 * I_ + i) * O_ + o2];
      if (PASS == 1) logits[((size_t)b2 * I_ + i) * O_ + o2] = ell;
      float m = ell;
      m = fmaxf(m, __shfl_xor(m, 32));
      m = fmaxf(m, __shfl_xor(m, 16));
      m = fmaxf(m, __shfl_xor(m, 8));
      m = fmaxf(m, __shfl_xor(m, 4));
      m = fmaxf(m, __shfl_xor(m, 2));
      m = fmaxf(m, __shfl_xor(m, 1));
      float e = __expf(ell - m);
      float s = e;
      s += __shfl_xor(s, 32); s += __shfl_xor(s, 16); s += __shfl_xor(s, 8);
      s += __shfl_xor(s, 4);  s += __shfl_xor(s, 2);  s += __shfl_xor(s, 1);
      r_lds[tid] = e / s;
      __syncthreads();

      // ---- accumulate preact partials: acc += route[b][o] * v ----
      #pragma unroll
      for (int b = 0; b < 16; ++b) {
        acc0[b] = fmaf(r_lds[b * 64 + og],      v0[b], acc0[b]);
        acc1[b] = fmaf(r_lds[b * 64 + og + 32], v1[b], acc1[b]);
      }
    }
  }

  const float sc = (PASS == 0) ? (1.0f / 64.0f) : 1.0f;
  float* __restrict__ po = part + (size_t)blk * (B_ * J_);
  #pragma unroll
  for (int b = 0; b < 16; ++b) {
    po[b * J_ + j0] = acc0[b] * sc;
    po[b * J_ + j1] = acc1[b] * sc;
  }
}

// -------------------------------------------------------------------------
// reduce_squash: preact[b][j] = sum_blk part[blk][b][j]; p += bias;
// squash over a (32-wide): out = p * sqrt(ns)/(1+ns), ns = sum_a p^2.
// One wave per (b,o) row; lanes 0-31 / 32-63 split the 256 partials.
// -------------------------------------------------------------------------
__global__ __launch_bounds__(256) void reduce_squash(
    const float* __restrict__ part, const float* __restrict__ bias,
    float* __restrict__ out)
{
  const int wave = (blockIdx.x * 256 + threadIdx.x) >> 6;   // 0..1023 = b*64+o
  const int L = threadIdx.x & 63;
  const int a = L & 31, q = L >> 5;
  const int e = wave * 32 + a;                              // b*2048 + o*32 + a

  float s0 = 0.f, s1 = 0.f;
  #pragma unroll 4
  for (int k = 0; k < 128; k += 2) {
    s0 += part[(size_t)(q * 128 + k)     * (B_ * J_) + e];
    s1 += part[(size_t)(q * 128 + k + 1) * (B_ * J_) + e];
  }
  float s = s0 + s1;
  s += __shfl_xor(s, 32);              // combine the two 128-partial halves

  float p = s + bias[e & 2047];
  float ns = p * p;
  ns += __shfl_xor(ns, 1);  ns += __shfl_xor(ns, 2);
  ns += __shfl_xor(ns, 4);  ns += __shfl_xor(ns, 8);
  ns += __shfl_xor(ns, 16);
  float scale = sqrtf(ns) / (1.0f + ns);
  if (L < 32) out[e] = p * scale;
}

// -------------------------------------------------------------------------
extern "C" void kernel_launch(void* const* d_in, const int* in_sizes, int n_in,
                              void* d_out, int out_size, void* d_ws, size_t ws_size,
                              hipStream_t stream) {
  const float* x    = (const float*)d_in[0];
  const float* W    = (const float*)d_in[1];
  const float* bias = (const float*)d_in[2];
  float* out = (float*)d_out;

  float* part   = (float*)d_ws;                      // 256*32768 f32 = 32 MB
  float* act    = part + (size_t)NBLK_ * (B_ * J_);  // 32768 f32
  float* logits = act + (B_ * J_);                   // 16*2048*64 f32 = 8 MB
  // total workspace: ~40.1 MB

  pass_kernel<0><<<NBLK_, 1024, 0, stream>>>(x, W, act, part, logits);
  reduce_squash<<<256, 256, 0, stream>>>(part, bias, act);
  pass_kernel<1><<<NBLK_, 1024, 0, stream>>>(x, W, act, part, logits);
  reduce_squash<<<256, 256, 0, stream>>>(part, bias, act);
  pass_kernel<2><<<NBLK_, 1024, 0, stream>>>(x, W, act, part, logits);
  reduce_squash<<<256, 256, 0, stream>>>(part, bias, out);
}

// Round 2
// 1357.674 us; speedup vs baseline: 1.5810x; 1.5810x over previous
//
#include <hip/hip_runtime.h>
#include <math.h>

#define B_   16
#define I_   2048
#define AIN_ 16
#define O_   64
#define J_   2048     // O*A_OUT
#define IPB_ 8        // i's per block
#define NBLK_ 256     // I_/IPB_

// -------------------------------------------------------------------------
// pass_kernel<PASS>: one full streaming pass over W, recomputing votes.
//   PASS 0: route = 1/64 (softmax of zero logits)  -> partial preact
//   PASS 1: dist = votes.act0; logits := dist; route = softmax(dist)
//   PASS 2: dist = votes.act1; route = softmax(logits + dist)
// Thread tid owns ADJACENT columns j0=2*tid, j1=2*tid+1 (same o = tid>>4),
// so W loads are float2. Batch dim processed in two halves of 8 so peak
// live registers stay ~75 (acc[16]f2=32 persistent + v[8]f2=16 + w=8).
// __launch_bounds__(1024,4) -> 128-VGPR cap (round-1's default gave 64 ->
// catastrophic scratch spills: 2 GB spill writes per pass).
// -------------------------------------------------------------------------
template<int PASS>
__global__ __launch_bounds__(1024, 4) void pass_kernel(
    const float* __restrict__ x, const float* __restrict__ W,
    const float* __restrict__ act_in, float* __restrict__ part,
    float* __restrict__ logits)
{
  __shared__ float x_lds[IPB_ * B_ * AIN_];   // 8 KB, [il][b][a]
  __shared__ float d_lds[8 * O_];             // 2 KB, distances (one b-half)
  __shared__ float r_lds[8 * O_];             // 2 KB, route     (one b-half)

  const int tid = threadIdx.x;
  const int blk = blockIdx.x;
  const int i0  = blk * IPB_;

  // stage x chunk for all 8 i's (coalesced)
  for (int e = tid; e < IPB_ * B_ * AIN_; e += 1024) {
    int b = e >> 7, il = (e >> 4) & 7, a = e & 15;
    x_lds[il * 256 + b * 16 + a] =
        x[(size_t)b * (I_ * AIN_) + (size_t)(i0 + il) * AIN_ + a];
  }
  __syncthreads();

  const int og = tid >> 4;      // o of this thread's two columns (0..63)
  const int lg = tid & 15;      // lane within the 16-lane o-group

  float2 acc[16];
  #pragma unroll
  for (int b = 0; b < 16; ++b) acc[b] = make_float2(0.f, 0.f);

  const float2* __restrict__ Wq   = (const float2*)W;
  const float2* __restrict__ actq = (const float2*)act_in;

  for (int il = 0; il < IPB_; ++il) {
    const int i = i0 + il;
    const float2* __restrict__ Wi = Wq + (size_t)i * (AIN_ * (J_ / 2));
    const float4* __restrict__ xq = (const float4*)x_lds + il * 64;

    for (int h = 0; h < 2; ++h) {
      // ---- votes for this b-half: v[bb] = sum_a x[b,a] * W[i,a,j] ----
      float2 v[8];
      #pragma unroll
      for (int bb = 0; bb < 8; ++bb) v[bb] = make_float2(0.f, 0.f);

      #pragma unroll
      for (int a4 = 0; a4 < 4; ++a4) {
        float2 w0 = Wi[(size_t)(a4 * 4 + 0) * (J_ / 2) + tid];
        float2 w1 = Wi[(size_t)(a4 * 4 + 1) * (J_ / 2) + tid];
        float2 w2 = Wi[(size_t)(a4 * 4 + 2) * (J_ / 2) + tid];
        float2 w3 = Wi[(size_t)(a4 * 4 + 3) * (J_ / 2) + tid];
        #pragma unroll
        for (int bb = 0; bb < 8; ++bb) {
          float4 xv = xq[(h * 8 + bb) * 4 + a4];   // LDS broadcast
          v[bb].x = fmaf(xv.x, w0.x, v[bb].x);
          v[bb].y = fmaf(xv.x, w0.y, v[bb].y);
          v[bb].x = fmaf(xv.y, w1.x, v[bb].x);
          v[bb].y = fmaf(xv.y, w1.y, v[bb].y);
          v[bb].x = fmaf(xv.z, w2.x, v[bb].x);
          v[bb].y = fmaf(xv.z, w2.y, v[bb].y);
          v[bb].x = fmaf(xv.w, w3.x, v[bb].x);
          v[bb].y = fmaf(xv.w, w3.y, v[bb].y);
        }
      }

      if (PASS == 0) {
        #pragma unroll
        for (int bb = 0; bb < 8; ++bb) {
          acc[h * 8 + bb].x += v[bb].x;
          acc[h * 8 + bb].y += v[bb].y;
        }
      } else {
        // ---- distances[b][o] = sum_a v*act : in-thread pair + 4-step xor ----
        #pragma unroll
        for (int bb = 0; bb < 8; ++bb) {
          const int b = h * 8 + bb;
          float2 av = actq[(size_t)b * (J_ / 2) + tid];
          float c = v[bb].x * av.x + v[bb].y * av.y;
          c += __shfl_xor(c, 1);  c += __shfl_xor(c, 2);
          c += __shfl_xor(c, 4);  c += __shfl_xor(c, 8);
          if (lg == bb) d_lds[bb * 64 + og] = c;
        }
        __syncthreads();

        // ---- softmax over o (waves 0..7: one wave per bb; lane = o) ----
        if (tid < 512) {
          const int bb2 = tid >> 6, o2 = tid & 63;
          const int b2  = h * 8 + bb2;
          float ell = d_lds[tid];
          if (PASS == 2) ell += logits[((size_t)b2 * I_ + i) * O_ + o2];
          if (PASS == 1) logits[((size_t)b2 * I_ + i) * O_ + o2] = ell;
          float m = ell;
          m = fmaxf(m, __shfl_xor(m, 32));
          m = fmaxf(m, __shfl_xor(m, 16));
          m = fmaxf(m, __shfl_xor(m, 8));
          m = fmaxf(m, __shfl_xor(m, 4));
          m = fmaxf(m, __shfl_xor(m, 2));
          m = fmaxf(m, __shfl_xor(m, 1));
          float e = __expf(ell - m);
          float s = e;
          s += __shfl_xor(s, 32); s += __shfl_xor(s, 16); s += __shfl_xor(s, 8);
          s += __shfl_xor(s, 4);  s += __shfl_xor(s, 2);  s += __shfl_xor(s, 1);
          r_lds[tid] = e / s;
        }
        __syncthreads();

        // ---- accumulate preact partials: acc += route[b][o] * v ----
        #pragma unroll
        for (int bb = 0; bb < 8; ++bb) {
          float r = r_lds[bb * 64 + og];
          acc[h * 8 + bb].x = fmaf(r, v[bb].x, acc[h * 8 + bb].x);
          acc[h * 8 + bb].y = fmaf(r, v[bb].y, acc[h * 8 + bb].y);
        }
      }
    }
  }

  const float sc = (PASS == 0) ? (1.0f / 64.0f) : 1.0f;
  float2* __restrict__ po = (float2*)(part + (size_t)blk * (B_ * J_));
  #pragma unroll
  for (int b = 0; b < 16; ++b) {
    po[(size_t)b * (J_ / 2) + tid] = make_float2(acc[b].x * sc, acc[b].y * sc);
  }
}

// -------------------------------------------------------------------------
// reduce_squash: preact[b][j] = sum_blk part[blk][b][j]; p += bias;
// squash over a (32-wide): out = p * sqrt(ns)/(1+ns), ns = sum_a p^2.
// One wave per (b,o) row; lanes 0-31 / 32-63 split the 256 partials.
// -------------------------------------------------------------------------
__global__ __launch_bounds__(256) void reduce_squash(
    const float* __restrict__ part, const float* __restrict__ bias,
    float* __restrict__ out)
{
  const int wave = (blockIdx.x * 256 + threadIdx.x) >> 6;   // 0..1023 = b*64+o
  const int L = threadIdx.x & 63;
  const int a = L & 31, q = L >> 5;
  const int e = wave * 32 + a;                              // b*2048 + o*32 + a

  float s0 = 0.f, s1 = 0.f;
  #pragma unroll 4
  for (int k = 0; k < 128; k += 2) {
    s0 += part[(size_t)(q * 128 + k)     * (B_ * J_) + e];
    s1 += part[(size_t)(q * 128 + k + 1) * (B_ * J_) + e];
  }
  float s = s0 + s1;
  s += __shfl_xor(s, 32);              // combine the two 128-partial halves

  float p = s + bias[e & 2047];
  float ns = p * p;
  ns += __shfl_xor(ns, 1);  ns += __shfl_xor(ns, 2);
  ns += __shfl_xor(ns, 4);  ns += __shfl_xor(ns, 8);
  ns += __shfl_xor(ns, 16);
  float scale = sqrtf(ns) / (1.0f + ns);
  if (L < 32) out[e] = p * scale;
}

// -------------------------------------------------------------------------
extern "C" void kernel_launch(void* const* d_in, const int* in_sizes, int n_in,
                              void* d_out, int out_size, void* d_ws, size_t ws_size,
                              hipStream_t stream) {
  const float* x    = (const float*)d_in[0];
  const float* W    = (const float*)d_in[1];
  const float* bias = (const float*)d_in[2];
  float* out = (float*)d_out;

  float* part   = (float*)d_ws;                      // 256*32768 f32 = 32 MB
  float* act    = part + (size_t)NBLK_ * (B_ * J_);  // 32768 f32
  float* logits = act + (B_ * J_);                   // 16*2048*64 f32 = 8 MB
  // total workspace: ~40.1 MB

  pass_kernel<0><<<NBLK_, 1024, 0, stream>>>(x, W, act, part, logits);
  reduce_squash<<<256, 256, 0, stream>>>(part, bias, act);
  pass_kernel<1><<<NBLK_, 1024, 0, stream>>>(x, W, act, part, logits);
  reduce_squash<<<256, 256, 0, stream>>>(part, bias, act);
  pass_kernel<2><<<NBLK_, 1024, 0, stream>>>(x, W, act, part, logits);
  reduce_squash<<<256, 256, 0, stream>>>(part, bias, out);
}

// Round 3
// 1300.802 us; speedup vs baseline: 1.6501x; 1.0437x over previous
//
#include <hip/hip_runtime.h>
#include <math.h>

#define B_   16
#define I_   2048
#define AIN_ 16
#define O_   64
#define J_   2048     // O*A_OUT
#define IPB_ 8        // i's per block
#define NBLK_ 256     // I_/IPB_

// -------------------------------------------------------------------------
// pass_kernel<PASS>: one full streaming pass over W, recomputing votes.
//   PASS 0: route = 1/64 (softmax of zero logits)  -> partial preact
//   PASS 1: dist = votes.act0; logits := dist; route = softmax(dist)
//   PASS 2: dist = votes.act1; route = softmax(logits + dist)
// Thread tid owns ADJACENT columns j0=2*tid, j1=2*tid+1 (same o = tid>>4),
// so W loads are float2. Batch dim processed in two halves of 8 so peak
// live registers stay ~90 (acc[16]f2=32 persistent + v[8]f2=16 + w=8).
//
// amdgpu_waves_per_eu(4,4): pin occupancy target to 4 waves/EU (= exactly
// one 1024-thread block per CU) -> 512/4 = 128 VGPR budget. Round 2 showed
// __launch_bounds__(1024,4) alone does NOT do this: the backend still
// TARGETED 8 waves/EU, allocated 64 VGPRs, and spilled ~1.7 GB/pass to
// scratch (WRITE_SIZE 1.05 GB vs 40 MB ideal, VALUBusy 4.8%).
// -------------------------------------------------------------------------
template<int PASS>
__global__ __launch_bounds__(1024)
__attribute__((amdgpu_waves_per_eu(4, 4)))
void pass_kernel(
    const float* __restrict__ x, const float* __restrict__ W,
    const float* __restrict__ act_in, float* __restrict__ part,
    float* __restrict__ logits)
{
  __shared__ float x_lds[IPB_ * B_ * AIN_];   // 8 KB, [il][b][a]
  __shared__ float d_lds[8 * O_];             // 2 KB, distances (one b-half)
  __shared__ float r_lds[8 * O_];             // 2 KB, route     (one b-half)

  const int tid = threadIdx.x;
  const int blk = blockIdx.x;
  const int i0  = blk * IPB_;

  // stage x chunk for all 8 i's (coalesced)
  for (int e = tid; e < IPB_ * B_ * AIN_; e += 1024) {
    int b = e >> 7, il = (e >> 4) & 7, a = e & 15;
    x_lds[il * 256 + b * 16 + a] =
        x[(size_t)b * (I_ * AIN_) + (size_t)(i0 + il) * AIN_ + a];
  }
  __syncthreads();

  const int og = tid >> 4;      // o of this thread's two columns (0..63)
  const int lg = tid & 15;      // lane within the 16-lane o-group

  float2 acc[16];
  #pragma unroll
  for (int b = 0; b < 16; ++b) acc[b] = make_float2(0.f, 0.f);

  const float2* __restrict__ Wq   = (const float2*)W;
  const float2* __restrict__ actq = (const float2*)act_in;

  for (int il = 0; il < IPB_; ++il) {
    const int i = i0 + il;
    const float2* __restrict__ Wi = Wq + (size_t)i * (AIN_ * (J_ / 2));
    const float4* __restrict__ xq = (const float4*)x_lds + il * 64;

    for (int h = 0; h < 2; ++h) {
      // ---- votes for this b-half: v[bb] = sum_a x[b,a] * W[i,a,j] ----
      float2 v[8];
      #pragma unroll
      for (int bb = 0; bb < 8; ++bb) v[bb] = make_float2(0.f, 0.f);

      #pragma unroll
      for (int a4 = 0; a4 < 4; ++a4) {
        float2 w0 = Wi[(size_t)(a4 * 4 + 0) * (J_ / 2) + tid];
        float2 w1 = Wi[(size_t)(a4 * 4 + 1) * (J_ / 2) + tid];
        float2 w2 = Wi[(size_t)(a4 * 4 + 2) * (J_ / 2) + tid];
        float2 w3 = Wi[(size_t)(a4 * 4 + 3) * (J_ / 2) + tid];
        #pragma unroll
        for (int bb = 0; bb < 8; ++bb) {
          float4 xv = xq[(h * 8 + bb) * 4 + a4];   // LDS broadcast
          v[bb].x = fmaf(xv.x, w0.x, v[bb].x);
          v[bb].y = fmaf(xv.x, w0.y, v[bb].y);
          v[bb].x = fmaf(xv.y, w1.x, v[bb].x);
          v[bb].y = fmaf(xv.y, w1.y, v[bb].y);
          v[bb].x = fmaf(xv.z, w2.x, v[bb].x);
          v[bb].y = fmaf(xv.z, w2.y, v[bb].y);
          v[bb].x = fmaf(xv.w, w3.x, v[bb].x);
          v[bb].y = fmaf(xv.w, w3.y, v[bb].y);
        }
      }

      if (PASS == 0) {
        #pragma unroll
        for (int bb = 0; bb < 8; ++bb) {
          acc[h * 8 + bb].x += v[bb].x;
          acc[h * 8 + bb].y += v[bb].y;
        }
      } else {
        // ---- distances[b][o] = sum_a v*act : in-thread pair + 4-step xor ----
        #pragma unroll
        for (int bb = 0; bb < 8; ++bb) {
          const int b = h * 8 + bb;
          float2 av = actq[(size_t)b * (J_ / 2) + tid];
          float c = v[bb].x * av.x + v[bb].y * av.y;
          c += __shfl_xor(c, 1);  c += __shfl_xor(c, 2);
          c += __shfl_xor(c, 4);  c += __shfl_xor(c, 8);
          if (lg == bb) d_lds[bb * 64 + og] = c;
        }
        __syncthreads();

        // ---- softmax over o (waves 0..7: one wave per bb; lane = o) ----
        if (tid < 512) {
          const int bb2 = tid >> 6, o2 = tid & 63;
          const int b2  = h * 8 + bb2;
          float ell = d_lds[tid];
          if (PASS == 2) ell += logits[((size_t)b2 * I_ + i) * O_ + o2];
          if (PASS == 1) logits[((size_t)b2 * I_ + i) * O_ + o2] = ell;
          float m = ell;
          m = fmaxf(m, __shfl_xor(m, 32));
          m = fmaxf(m, __shfl_xor(m, 16));
          m = fmaxf(m, __shfl_xor(m, 8));
          m = fmaxf(m, __shfl_xor(m, 4));
          m = fmaxf(m, __shfl_xor(m, 2));
          m = fmaxf(m, __shfl_xor(m, 1));
          float e = __expf(ell - m);
          float s = e;
          s += __shfl_xor(s, 32); s += __shfl_xor(s, 16); s += __shfl_xor(s, 8);
          s += __shfl_xor(s, 4);  s += __shfl_xor(s, 2);  s += __shfl_xor(s, 1);
          r_lds[tid] = e / s;
        }
        __syncthreads();

        // ---- accumulate preact partials: acc += route[b][o] * v ----
        #pragma unroll
        for (int bb = 0; bb < 8; ++bb) {
          float r = r_lds[bb * 64 + og];
          acc[h * 8 + bb].x = fmaf(r, v[bb].x, acc[h * 8 + bb].x);
          acc[h * 8 + bb].y = fmaf(r, v[bb].y, acc[h * 8 + bb].y);
        }
      }
    }
  }

  const float sc = (PASS == 0) ? (1.0f / 64.0f) : 1.0f;
  float2* __restrict__ po = (float2*)(part + (size_t)blk * (B_ * J_));
  #pragma unroll
  for (int b = 0; b < 16; ++b) {
    po[(size_t)b * (J_ / 2) + tid] = make_float2(acc[b].x * sc, acc[b].y * sc);
  }
}

// -------------------------------------------------------------------------
// reduce_squash: preact[b][j] = sum_blk part[blk][b][j]; p += bias;
// squash over a (32-wide): out = p * sqrt(ns)/(1+ns), ns = sum_a p^2.
// One wave per (b,o) row; lanes 0-31 / 32-63 split the 256 partials.
// -------------------------------------------------------------------------
__global__ __launch_bounds__(256) void reduce_squash(
    const float* __restrict__ part, const float* __restrict__ bias,
    float* __restrict__ out)
{
  const int wave = (blockIdx.x * 256 + threadIdx.x) >> 6;   // 0..1023 = b*64+o
  const int L = threadIdx.x & 63;
  const int a = L & 31, q = L >> 5;
  const int e = wave * 32 + a;                              // b*2048 + o*32 + a

  float s0 = 0.f, s1 = 0.f;
  #pragma unroll 4
  for (int k = 0; k < 128; k += 2) {
    s0 += part[(size_t)(q * 128 + k)     * (B_ * J_) + e];
    s1 += part[(size_t)(q * 128 + k + 1) * (B_ * J_) + e];
  }
  float s = s0 + s1;
  s += __shfl_xor(s, 32);              // combine the two 128-partial halves

  float p = s + bias[e & 2047];
  float ns = p * p;
  ns += __shfl_xor(ns, 1);  ns += __shfl_xor(ns, 2);
  ns += __shfl_xor(ns, 4);  ns += __shfl_xor(ns, 8);
  ns += __shfl_xor(ns, 16);
  float scale = sqrtf(ns) / (1.0f + ns);
  if (L < 32) out[e] = p * scale;
}

// -------------------------------------------------------------------------
extern "C" void kernel_launch(void* const* d_in, const int* in_sizes, int n_in,
                              void* d_out, int out_size, void* d_ws, size_t ws_size,
                              hipStream_t stream) {
  const float* x    = (const float*)d_in[0];
  const float* W    = (const float*)d_in[1];
  const float* bias = (const float*)d_in[2];
  float* out = (float*)d_out;

  float* part   = (float*)d_ws;                      // 256*32768 f32 = 32 MB
  float* act    = part + (size_t)NBLK_ * (B_ * J_);  // 32768 f32
  float* logits = act + (B_ * J_);                   // 16*2048*64 f32 = 8 MB
  // total workspace: ~40.1 MB

  pass_kernel<0><<<NBLK_, 1024, 0, stream>>>(x, W, act, part, logits);
  reduce_squash<<<256, 256, 0, stream>>>(part, bias, act);
  pass_kernel<1><<<NBLK_, 1024, 0, stream>>>(x, W, act, part, logits);
  reduce_squash<<<256, 256, 0, stream>>>(part, bias, act);
  pass_kernel<2><<<NBLK_, 1024, 0, stream>>>(x, W, act, part, logits);
  reduce_squash<<<256, 256, 0, stream>>>(part, bias, out);
}

// Round 4
// 233.258 us; speedup vs baseline: 9.2021x; 5.5767x over previous
//
#include <hip/hip_runtime.h>
#include <math.h>

#define B_   16
#define I_   2048
#define AIN_ 16
#define O_   64
#define J_   2048     // O*A_OUT
#define JP_  1024     // j-pairs (thread owns cols 2t, 2t+1)
#define IPB_ 8        // i's per block
#define NBLK_ 256     // I_/IPB_

// bf16 pack/unpack (RNE). Inputs finite -> no NaN handling needed.
__device__ __forceinline__ unsigned bf16rne(float f) {
  unsigned u = __float_as_uint(f);
  return (u + 0x7FFFu + ((u >> 16) & 1u)) >> 16;
}
__device__ __forceinline__ float bf16lo(unsigned p) { return __uint_as_float(p << 16); }
__device__ __forceinline__ float bf16hi(unsigned p) { return __uint_as_float(p & 0xFFFF0000u); }

// -------------------------------------------------------------------------
// votes_kernel: votes[b,i,j] = sum_a x[b,i,a] * W[i,a,j], stored packed
// bf16x2 at votes[i*16*1024 + b*1024 + jp]. W read EXACTLY once (268 MB).
// Register budget by design: v[16]f2=32 + w(2 float2)=4 + xv=2 + addr ~8
// => ~46 live VGPRs, under the 64-VGPR budget the backend insists on
// (rounds 1-3: 75-90 live regs at 64 budget => ~1 GB/pass scratch spill).
// -------------------------------------------------------------------------
__global__ __launch_bounds__(1024) void votes_kernel(
    const float* __restrict__ x, const float* __restrict__ W,
    unsigned* __restrict__ votes)
{
  __shared__ float x_lds[IPB_ * B_ * AIN_];   // 8 KB, [il][b][a]
  const int tid = threadIdx.x, blk = blockIdx.x, i0 = blk * IPB_;

  for (int e = tid; e < IPB_ * B_ * AIN_; e += 1024) {
    int b = e >> 7, il = (e >> 4) & 7, a = e & 15;
    x_lds[il * 256 + b * 16 + a] =
        x[(size_t)b * (I_ * AIN_) + (size_t)(i0 + il) * AIN_ + a];
  }
  __syncthreads();

  const float2* __restrict__ Wq = (const float2*)W;
  for (int il = 0; il < IPB_; ++il) {
    const int i = i0 + il;
    const float2* __restrict__ Wi = Wq + (size_t)i * (AIN_ * JP_);
    const float2* __restrict__ xq = (const float2*)x_lds + il * 128; // [b][a2]

    float2 v[16];
    #pragma unroll
    for (int b = 0; b < 16; ++b) v[b] = make_float2(0.f, 0.f);

    #pragma unroll
    for (int a2 = 0; a2 < 8; ++a2) {        // pairs of a: low w-liveness
      float2 w0 = Wi[(size_t)(2 * a2 + 0) * JP_ + tid];
      float2 w1 = Wi[(size_t)(2 * a2 + 1) * JP_ + tid];
      #pragma unroll
      for (int b = 0; b < 16; ++b) {
        float2 xv = xq[b * 8 + a2];          // LDS broadcast
        v[b].x = fmaf(xv.x, w0.x, v[b].x);
        v[b].y = fmaf(xv.x, w0.y, v[b].y);
        v[b].x = fmaf(xv.y, w1.x, v[b].x);
        v[b].y = fmaf(xv.y, w1.y, v[b].y);
      }
    }

    unsigned* __restrict__ vo = votes + (size_t)i * (B_ * JP_) + tid;
    #pragma unroll
    for (int b = 0; b < 16; ++b)
      vo[(size_t)b * JP_] = bf16rne(v[b].x) | (bf16rne(v[b].y) << 16);
  }
}

// -------------------------------------------------------------------------
// route_kernel<PASS>: one routing iteration reading bf16 votes.
//   PASS 0: route = 1/64                      -> partial preact
//   PASS 1: dist = votes.act0; logits := dist; route = softmax(dist)
//   PASS 2: dist = votes.act1; route = softmax(logits + dist)
// h (batch-half) is the OUTER loop so per-half live state is
// acc[8]f2=16 + av[8]f2=16 + vp[8]=8 + transients ~14 => ~55 VGPRs.
// Each votes element is read exactly once per pass (halves read disjoint b).
// -------------------------------------------------------------------------
template<int PASS>
__global__ __launch_bounds__(1024) void route_kernel(
    const unsigned* __restrict__ votes, const float* __restrict__ act_in,
    float* __restrict__ part, float* __restrict__ logits)
{
  __shared__ float d_lds[8 * O_];             // 2 KB, distances (one b-half)
  __shared__ float r_lds[8 * O_];             // 2 KB, route     (one b-half)

  const int tid = threadIdx.x, blk = blockIdx.x, i0 = blk * IPB_;
  const int og = tid >> 4;      // o of this thread's two columns (0..63)
  const int lg = tid & 15;      // lane within the 16-lane o-group
  const float2* __restrict__ actq = (const float2*)act_in;
  float2* __restrict__ po = (float2*)(part + (size_t)blk * (B_ * J_));

  for (int h = 0; h < 2; ++h) {
    float2 acc[8];
    #pragma unroll
    for (int bb = 0; bb < 8; ++bb) acc[bb] = make_float2(0.f, 0.f);

    float2 av[8];
    if (PASS > 0) {
      #pragma unroll
      for (int bb = 0; bb < 8; ++bb)
        av[bb] = actq[(size_t)(h * 8 + bb) * JP_ + tid];
    }

    for (int il = 0; il < IPB_; ++il) {
      const int i = i0 + il;
      const unsigned* __restrict__ vo =
          votes + (size_t)i * (B_ * JP_) + (size_t)(h * 8) * JP_ + tid;
      unsigned vp[8];
      #pragma unroll
      for (int bb = 0; bb < 8; ++bb) vp[bb] = vo[(size_t)bb * JP_];

      if (PASS == 0) {
        #pragma unroll
        for (int bb = 0; bb < 8; ++bb) {
          acc[bb].x += bf16lo(vp[bb]);
          acc[bb].y += bf16hi(vp[bb]);
        }
      } else {
        // distances[b][o] = sum_a v*act: in-thread pair + 4-step xor over 16
        #pragma unroll
        for (int bb = 0; bb < 8; ++bb) {
          float c = bf16lo(vp[bb]) * av[bb].x + bf16hi(vp[bb]) * av[bb].y;
          c += __shfl_xor(c, 1);  c += __shfl_xor(c, 2);
          c += __shfl_xor(c, 4);  c += __shfl_xor(c, 8);
          if (lg == bb) d_lds[bb * 64 + og] = c;
        }
        __syncthreads();

        // softmax over o (waves 0..7: one wave per bb; lane = o)
        if (tid < 512) {
          const int bb2 = tid >> 6, o2 = tid & 63;
          const int b2  = h * 8 + bb2;
          float ell = d_lds[tid];
          if (PASS == 2) ell += logits[((size_t)b2 * I_ + i) * O_ + o2];
          if (PASS == 1) logits[((size_t)b2 * I_ + i) * O_ + o2] = ell;
          float m = ell;
          m = fmaxf(m, __shfl_xor(m, 32)); m = fmaxf(m, __shfl_xor(m, 16));
          m = fmaxf(m, __shfl_xor(m, 8));  m = fmaxf(m, __shfl_xor(m, 4));
          m = fmaxf(m, __shfl_xor(m, 2));  m = fmaxf(m, __shfl_xor(m, 1));
          float e = __expf(ell - m);
          float s = e;
          s += __shfl_xor(s, 32); s += __shfl_xor(s, 16); s += __shfl_xor(s, 8);
          s += __shfl_xor(s, 4);  s += __shfl_xor(s, 2);  s += __shfl_xor(s, 1);
          r_lds[tid] = e / s;
        }
        __syncthreads();

        #pragma unroll
        for (int bb = 0; bb < 8; ++bb) {
          float r = r_lds[bb * 64 + og];
          acc[bb].x = fmaf(r, bf16lo(vp[bb]), acc[bb].x);
          acc[bb].y = fmaf(r, bf16hi(vp[bb]), acc[bb].y);
        }
      }
    }

    const float sc = (PASS == 0) ? (1.0f / 64.0f) : 1.0f;
    #pragma unroll
    for (int bb = 0; bb < 8; ++bb)
      po[(size_t)(h * 8 + bb) * JP_ + tid] =
          make_float2(acc[bb].x * sc, acc[bb].y * sc);
  }
}

// -------------------------------------------------------------------------
// reduce_squash: preact[b][j] = sum_blk part[blk][b][j]; p += bias;
// squash over a (32-wide): out = p * sqrt(ns)/(1+ns), ns = sum_a p^2.
// -------------------------------------------------------------------------
__global__ __launch_bounds__(256) void reduce_squash(
    const float* __restrict__ part, const float* __restrict__ bias,
    float* __restrict__ out)
{
  const int wave = (blockIdx.x * 256 + threadIdx.x) >> 6;   // 0..1023 = b*64+o
  const int L = threadIdx.x & 63;
  const int a = L & 31, q = L >> 5;
  const int e = wave * 32 + a;                              // b*2048 + o*32 + a

  float s0 = 0.f, s1 = 0.f;
  #pragma unroll 4
  for (int k = 0; k < 128; k += 2) {
    s0 += part[(size_t)(q * 128 + k)     * (B_ * J_) + e];
    s1 += part[(size_t)(q * 128 + k + 1) * (B_ * J_) + e];
  }
  float s = s0 + s1;
  s += __shfl_xor(s, 32);              // combine the two 128-partial halves

  float p = s + bias[e & 2047];
  float ns = p * p;
  ns += __shfl_xor(ns, 1);  ns += __shfl_xor(ns, 2);
  ns += __shfl_xor(ns, 4);  ns += __shfl_xor(ns, 8);
  ns += __shfl_xor(ns, 16);
  float scale = sqrtf(ns) / (1.0f + ns);
  if (L < 32) out[e] = p * scale;
}

// -------------------------------------------------------------------------
// FALLBACK (ws too small): round-3 W-streaming pass kernel. Correct but slow.
// -------------------------------------------------------------------------
template<int PASS>
__global__ __launch_bounds__(1024) void fb_pass_kernel(
    const float* __restrict__ x, const float* __restrict__ W,
    const float* __restrict__ act_in, float* __restrict__ part,
    float* __restrict__ logits)
{
  __shared__ float x_lds[IPB_ * B_ * AIN_];
  __shared__ float d_lds[8 * O_];
  __shared__ float r_lds[8 * O_];
  const int tid = threadIdx.x, blk = blockIdx.x, i0 = blk * IPB_;
  for (int e = tid; e < IPB_ * B_ * AIN_; e += 1024) {
    int b = e >> 7, il = (e >> 4) & 7, a = e & 15;
    x_lds[il * 256 + b * 16 + a] =
        x[(size_t)b * (I_ * AIN_) + (size_t)(i0 + il) * AIN_ + a];
  }
  __syncthreads();
  const int og = tid >> 4, lg = tid & 15;
  float2 acc[16];
  #pragma unroll
  for (int b = 0; b < 16; ++b) acc[b] = make_float2(0.f, 0.f);
  const float2* __restrict__ Wq   = (const float2*)W;
  const float2* __restrict__ actq = (const float2*)act_in;
  for (int il = 0; il < IPB_; ++il) {
    const int i = i0 + il;
    const float2* __restrict__ Wi = Wq + (size_t)i * (AIN_ * JP_);
    const float4* __restrict__ xq = (const float4*)x_lds + il * 64;
    for (int h = 0; h < 2; ++h) {
      float2 v[8];
      #pragma unroll
      for (int bb = 0; bb < 8; ++bb) v[bb] = make_float2(0.f, 0.f);
      #pragma unroll
      for (int a4 = 0; a4 < 4; ++a4) {
        float2 w0 = Wi[(size_t)(a4 * 4 + 0) * JP_ + tid];
        float2 w1 = Wi[(size_t)(a4 * 4 + 1) * JP_ + tid];
        float2 w2 = Wi[(size_t)(a4 * 4 + 2) * JP_ + tid];
        float2 w3 = Wi[(size_t)(a4 * 4 + 3) * JP_ + tid];
        #pragma unroll
        for (int bb = 0; bb < 8; ++bb) {
          float4 xv = xq[(h * 8 + bb) * 4 + a4];
          v[bb].x = fmaf(xv.x, w0.x, v[bb].x); v[bb].y = fmaf(xv.x, w0.y, v[bb].y);
          v[bb].x = fmaf(xv.y, w1.x, v[bb].x); v[bb].y = fmaf(xv.y, w1.y, v[bb].y);
          v[bb].x = fmaf(xv.z, w2.x, v[bb].x); v[bb].y = fmaf(xv.z, w2.y, v[bb].y);
          v[bb].x = fmaf(xv.w, w3.x, v[bb].x); v[bb].y = fmaf(xv.w, w3.y, v[bb].y);
        }
      }
      if (PASS == 0) {
        #pragma unroll
        for (int bb = 0; bb < 8; ++bb) {
          acc[h * 8 + bb].x += v[bb].x; acc[h * 8 + bb].y += v[bb].y;
        }
      } else {
        #pragma unroll
        for (int bb = 0; bb < 8; ++bb) {
          const int b = h * 8 + bb;
          float2 avv = actq[(size_t)b * JP_ + tid];
          float c = v[bb].x * avv.x + v[bb].y * avv.y;
          c += __shfl_xor(c, 1); c += __shfl_xor(c, 2);
          c += __shfl_xor(c, 4); c += __shfl_xor(c, 8);
          if (lg == bb) d_lds[bb * 64 + og] = c;
        }
        __syncthreads();
        if (tid < 512) {
          const int bb2 = tid >> 6, o2 = tid & 63;
          const int b2  = h * 8 + bb2;
          float ell = d_lds[tid];
          if (PASS == 2) ell += logits[((size_t)b2 * I_ + i) * O_ + o2];
          if (PASS == 1) logits[((size_t)b2 * I_ + i) * O_ + o2] = ell;
          float m = ell;
          m = fmaxf(m, __shfl_xor(m, 32)); m = fmaxf(m, __shfl_xor(m, 16));
          m = fmaxf(m, __shfl_xor(m, 8));  m = fmaxf(m, __shfl_xor(m, 4));
          m = fmaxf(m, __shfl_xor(m, 2));  m = fmaxf(m, __shfl_xor(m, 1));
          float e = __expf(ell - m);
          float s = e;
          s += __shfl_xor(s, 32); s += __shfl_xor(s, 16); s += __shfl_xor(s, 8);
          s += __shfl_xor(s, 4);  s += __shfl_xor(s, 2);  s += __shfl_xor(s, 1);
          r_lds[tid] = e / s;
        }
        __syncthreads();
        #pragma unroll
        for (int bb = 0; bb < 8; ++bb) {
          float r = r_lds[bb * 64 + og];
          acc[h * 8 + bb].x = fmaf(r, v[bb].x, acc[h * 8 + bb].x);
          acc[h * 8 + bb].y = fmaf(r, v[bb].y, acc[h * 8 + bb].y);
        }
      }
    }
  }
  const float sc = (PASS == 0) ? (1.0f / 64.0f) : 1.0f;
  float2* __restrict__ po = (float2*)(part + (size_t)blk * (B_ * J_));
  #pragma unroll
  for (int b = 0; b < 16; ++b)
    po[(size_t)b * JP_ + tid] = make_float2(acc[b].x * sc, acc[b].y * sc);
}

// -------------------------------------------------------------------------
extern "C" void kernel_launch(void* const* d_in, const int* in_sizes, int n_in,
                              void* d_out, int out_size, void* d_ws, size_t ws_size,
                              hipStream_t stream) {
  const float* x    = (const float*)d_in[0];
  const float* W    = (const float*)d_in[1];
  const float* bias = (const float*)d_in[2];
  float* out = (float*)d_out;

  float*    part   = (float*)d_ws;                       // 32 MB
  float*    act    = part + (size_t)NBLK_ * (B_ * J_);   // 128 KB
  float*    logits = act + (B_ * J_);                    // 8 MB
  unsigned* votes  = (unsigned*)(logits + (size_t)B_ * I_ * O_);  // 134 MB
  const size_t need = ((size_t)NBLK_ * B_ * J_ + B_ * J_ + (size_t)B_ * I_ * O_) * 4
                    + (size_t)I_ * B_ * JP_ * 4;

  if (ws_size >= need) {
    votes_kernel<<<NBLK_, 1024, 0, stream>>>(x, W, votes);
    route_kernel<0><<<NBLK_, 1024, 0, stream>>>(votes, act, part, logits);
    reduce_squash<<<256, 256, 0, stream>>>(part, bias, act);
    route_kernel<1><<<NBLK_, 1024, 0, stream>>>(votes, act, part, logits);
    reduce_squash<<<256, 256, 0, stream>>>(part, bias, act);
    route_kernel<2><<<NBLK_, 1024, 0, stream>>>(votes, act, part, logits);
    reduce_squash<<<256, 256, 0, stream>>>(part, bias, out);
  } else {
    fb_pass_kernel<0><<<NBLK_, 1024, 0, stream>>>(x, W, act, part, logits);
    reduce_squash<<<256, 256, 0, stream>>>(part, bias, act);
    fb_pass_kernel<1><<<NBLK_, 1024, 0, stream>>>(x, W, act, part, logits);
    reduce_squash<<<256, 256, 0, stream>>>(part, bias, act);
    fb_pass_kernel<2><<<NBLK_, 1024, 0, stream>>>(x, W, act, part, logits);
    reduce_squash<<<256, 256, 0, stream>>>(part, bias, out);
  }
}